// Round 1
// 364.831 us; speedup vs baseline: 1.0424x; 1.0424x over previous
//
#include <hip/hip_runtime.h>
#include <hip/hip_bf16.h>
#include <math.h>

#define VV 50257   // vocab
#define VP 50304   // vocab padded to multiple of 128 (and 16)
#define HH 512     // d_model
#define SS 512     // source length
#define BB 8       // batch
#define TT 64      // decode steps
#define MM (TT*BB) // 512 GEMM rows

typedef __bf16 bf16x2 __attribute__((ext_vector_type(2)));
typedef __bf16 bf16x4 __attribute__((ext_vector_type(4)));
typedef __bf16 bf16x8 __attribute__((ext_vector_type(8)));
typedef float  f32x4  __attribute__((ext_vector_type(4)));

// fp32 -> bf16 RNE
__device__ __forceinline__ __bf16 f2b(float f) {
    unsigned u = __builtin_bit_cast(unsigned, f);
    unsigned r = (u + 0x7fffu + ((u >> 16) & 1u)) >> 16;
    unsigned short s = (unsigned short)r;
    return __builtin_bit_cast(__bf16, s);
}

// async global->LDS, 16B per lane; lds base must be wave-uniform
__device__ __forceinline__ void gl2lds16(const void* g, void* l) {
    __builtin_amdgcn_global_load_lds(
        (const __attribute__((address_space(1))) unsigned*)g,
        (__attribute__((address_space(3))) unsigned*)l, 16, 0, 0);
}

// ---------------------------------------------------------------------------
// K0a: cast decode_output fp32 [512*512] -> bf16
// ---------------------------------------------------------------------------
__global__ __launch_bounds__(256) void k_castA(const float* __restrict__ A,
                                               __bf16* __restrict__ Ab) {
    int i = (blockIdx.x * 256 + threadIdx.x) * 4;
    float4 v = *(const float4*)&A[i];
    bf16x4 o = {f2b(v.x), f2b(v.y), f2b(v.z), f2b(v.w)};
    *(bf16x4*)&Ab[i] = o;
}

// ---------------------------------------------------------------------------
// K0b: W fp32 [HH][VV] -> Wt bf16 [VP][HH] (transpose via LDS tile 64x64)
// ---------------------------------------------------------------------------
__global__ __launch_bounds__(256) void k_castWT(const float* __restrict__ W,
                                                __bf16* __restrict__ Wt) {
    __shared__ float tile[64][65];
    int n0 = blockIdx.x * 64;
    int k0 = blockIdx.y * 64;
    int tid = threadIdx.x;
#pragma unroll
    for (int i = 0; i < 16; i++) {
        int idx = tid + i * 256;
        int kk = idx >> 6, nn = idx & 63;
        int n = n0 + nn;
        tile[kk][nn] = (n < VV) ? W[(size_t)(k0 + kk) * VV + n] : 0.f;
    }
    __syncthreads();
#pragma unroll
    for (int i = 0; i < 8; i++) {
        int idx = tid + i * 256;
        int nn = idx >> 5, kp = idx & 31;
        bf16x2 o = {f2b(tile[2 * kp][nn]), f2b(tile[2 * kp + 1][nn])};
        *(bf16x2*)&Wt[(size_t)(n0 + nn) * HH + k0 + 2 * kp] = o;
    }
}

// ---------------------------------------------------------------------------
// K1: mw[s,b] = dot(memory[s,b,:], W_prob)
// ---------------------------------------------------------------------------
__global__ void k_mw(const float* __restrict__ mem, const float* __restrict__ Wp,
                     float* __restrict__ mw) {
    int row = blockIdx.x;
    int lane = threadIdx.x;
    const float* mp = mem + (size_t)row * HH;
    float acc = 0.f;
#pragma unroll
    for (int i = 0; i < HH / 64; i++)
        acc += mp[lane + 64 * i] * Wp[lane + 64 * i];
#pragma unroll
    for (int off = 32; off > 0; off >>= 1) acc += __shfl_down(acc, off);
    if (lane == 0) mw[row] = acc;
}

// ---------------------------------------------------------------------------
// K2: prob[t,b] = sigmoid( sum_s attn[b,t,s]*mw[s,b] + b_prob )
// ---------------------------------------------------------------------------
__global__ void k_prob(const float* __restrict__ attn, const float* __restrict__ mw,
                       const float* __restrict__ bp, float* __restrict__ prob) {
    int r = blockIdx.x;
    int t = r / BB, b = r % BB;
    int lane = threadIdx.x;
    const float* ap = attn + ((size_t)b * TT + t) * SS;
    float acc = 0.f;
#pragma unroll
    for (int i = 0; i < SS / 64; i++) {
        int s = lane + 64 * i;
        acc += ap[s] * mw[s * BB + b];
    }
#pragma unroll
    for (int off = 32; off > 0; off >>= 1) acc += __shfl_down(acc, off);
    if (lane == 0) prob[r] = 1.f / (1.f + expf(-(acc + bp[0])));
}

// ---------------------------------------------------------------------------
// K3: MFMA GEMM 128x128 tile, BK=64, double-buffered, fragment-order LDS.
// NOW: 512 threads / 8 waves per block (wave w owns a 64x32 sub-tile,
// wr=(w>>2)*64, wc=(w&3)*32) -> 16 waves/CU resident at 2 blocks/CU,
// double the latency-hiding TLP of the 256-thread version.
// Bijective XCD swizzle (nwg=1572=8*196+4): the 4 row-tiles sharing a Wt
// col-panel run temporally adjacent on the SAME XCD -> L2 reuse of Wt.
// Epilogue: bias add, logits -> bf16 ws (or fp32 d_out), LDS-reduced Z atomics.
// ---------------------------------------------------------------------------
template<bool BF16OUT>
__global__ __launch_bounds__(512, 4) void k_gemm3(const __bf16* __restrict__ Ab,
                                                  const __bf16* __restrict__ Wt,
                                                  const float* __restrict__ bias,
                                                  float* __restrict__ Cf,
                                                  __bf16* __restrict__ Cb,
                                                  float* __restrict__ Zrow) {
    __shared__ __bf16 As[2][8192];   // 8 segs x (2 halves x 16 rows x 32B) = 16 KB
    __shared__ __bf16 Bs[2][8192];
    __shared__ float zred[128];

    const int tid  = threadIdx.x;
    const int lane = tid & 63;
    const int wave = tid >> 6;          // 0..7
    const int l15  = lane & 15;
    const int quad = lane >> 4;
    const int wr = (wave >> 2) * 64;    // 0 or 64
    const int wc = (wave & 3) * 32;     // 0,32,64,96

    // --- bijective XCD swizzle over the 1572-block grid (q=196, r=4) ---
    int L = blockIdx.x + gridDim.x * blockIdx.y;   // dispatch-order id, XCD = L%8
    int xcd = L & 7, i8 = L >> 3;
    int nid = (xcd < 4 ? xcd * 197 : 4 * 197 + (xcd - 4) * 196) + i8;
    const int row0 = (nid & 3) * 128;   // row-tile fastest within an XCD chunk
    const int col0 = (nid >> 2) * 128;

    // staging: wave w handles seg w of both operands; per seg 2 DMA halves
    // j=0,1. Lane L loads global (row=seg*16+l15, k=(j*4+quad)*8..+8)
    // into LDS slot seg*2048B + j*1024B + 16B*L  (fragment order).
    size_t offA[2], offB[2];
#pragma unroll
    for (int j = 0; j < 2; j++) {
        offA[j] = (size_t)(row0 + wave * 16 + l15) * HH + (j * 4 + quad) * 8;
        offB[j] = (size_t)(col0 + wave * 16 + l15) * HH + (j * 4 + quad) * 8;
    }

#define STAGE(buf, k0)                                                    \
    do {                                                                  \
        _Pragma("unroll") for (int j = 0; j < 2; j++) {                   \
            gl2lds16(Ab + offA[j] + (k0), &As[buf][wave * 1024 + j * 512]); \
            gl2lds16(Wt + offB[j] + (k0), &Bs[buf][wave * 1024 + j * 512]); \
        }                                                                 \
    } while (0)

    f32x4 acc[4][2] = {};

    STAGE(0, 0);
    for (int it = 0; it < 8; ++it) {
        __syncthreads();                        // drains buf[it&1] DMAs
        if (it != 7) STAGE((it + 1) & 1, (it + 1) * 64);
        const __bf16* Al = &As[it & 1][0];
        const __bf16* Bl = &Bs[it & 1][0];
#pragma unroll
        for (int h = 0; h < 2; ++h) {
            bf16x8 af[4], bfv[2];
#pragma unroll
            for (int mt = 0; mt < 4; mt++)
                af[mt] = *(const bf16x8*)&Al[((wr >> 4) + mt) * 1024 + h * 512 + lane * 8];
#pragma unroll
            for (int nt = 0; nt < 2; nt++)
                bfv[nt] = *(const bf16x8*)&Bl[((wc >> 4) + nt) * 1024 + h * 512 + lane * 8];
#pragma unroll
            for (int mt = 0; mt < 4; mt++)
#pragma unroll
                for (int nt = 0; nt < 2; nt++)
                    acc[mt][nt] = __builtin_amdgcn_mfma_f32_16x16x32_bf16(
                        af[mt], bfv[nt], acc[mt][nt], 0, 0, 0);
        }
    }
#undef STAGE

    __syncthreads();
    if (tid < 128) zred[tid] = 0.f;
    __syncthreads();

#pragma unroll
    for (int mt = 0; mt < 4; mt++) {
        float esum[4] = {0.f, 0.f, 0.f, 0.f};
#pragma unroll
        for (int nt = 0; nt < 2; nt++) {
            int c = col0 + wc + nt * 16 + l15;
            if (c < VV) {
                float bv = bias[c];
#pragma unroll
                for (int i = 0; i < 4; i++) {
                    int r = row0 + wr + mt * 16 + quad * 4 + i;
                    float l = acc[mt][nt][i] + bv;
                    if (BF16OUT) Cb[(size_t)r * VP + c] = f2b(l);
                    else         Cf[(size_t)r * VV + c] = l;
                    esum[i] += __expf(l);
                }
            }
        }
#pragma unroll
        for (int i = 0; i < 4; i++) {
            float e = esum[i];
            e += __shfl_xor(e, 1);
            e += __shfl_xor(e, 2);
            e += __shfl_xor(e, 4);
            e += __shfl_xor(e, 8);
            if (l15 == 0)
                atomicAdd(&zred[wr + mt * 16 + quad * 4 + i], e);
        }
    }
    __syncthreads();
    if (tid < 128) atomicAdd(&Zrow[row0 + tid], zred[tid]);
}

// ---------------------------------------------------------------------------
// K4 shared preamble (256-thread version, used by fallback k_final_s):
// build per-row copy-mass hash + bitmap + Zc in LDS.
// ---------------------------------------------------------------------------
#define HT 1024
#define NBW 1572   // ceil(VV/32)

__device__ __forceinline__ void build_hash(const int* __restrict__ src,
                                           const float* __restrict__ ap,
                                           int b, int tid,
                                           int* keys, float* vals, unsigned* bmap,
                                           float* red, int* s_D, float* s_Zc) {
    for (int i = tid; i < HT; i += 256) { keys[i] = -1; vals[i] = 0.f; }
    for (int i = tid; i < NBW; i += 256) bmap[i] = 0u;
    if (tid == 0) *s_D = 0;
    __syncthreads();

    for (int s = tid; s < SS; s += 256) {
        int idx = src[s * BB + b];
        float v = ap[s];
        unsigned h = ((unsigned)idx * 2654435761u) >> 22;
        while (true) {
            int old = atomicCAS(&keys[h], -1, idx);
            if (old == -1 || old == idx) { atomicAdd(&vals[h], v); break; }
            h = (h + 1) & (HT - 1);
        }
    }
    __syncthreads();

    float lsum = 0.f; int dloc = 0;
    for (int i = tid; i < HT; i += 256) {
        int k = keys[i];
        if (k != -1) {
            lsum += __expf(vals[i]); dloc++;
            atomicOr(&bmap[(unsigned)k >> 5], 1u << (k & 31));
        }
    }
    atomicAdd(s_D, dloc);
    red[tid] = lsum; __syncthreads();
    for (int st = 128; st > 0; st >>= 1) {
        if (tid < st) red[tid] += red[tid + st];
        __syncthreads();
    }
    if (tid == 0) *s_Zc = (float)(VV - *s_D) + red[0];
    __syncthreads();
}

// ---------------------------------------------------------------------------
// K4a: finalize from bf16 padded logits — ONE block per row, 1024 threads.
// Hash/bitmap/Zc built ONCE per row (was 8x redundant). Streaming loop is
// bf16x8 loads + coalesced fp32 stores. D-count via ballot (no atomic storm).
// ---------------------------------------------------------------------------
__global__ __launch_bounds__(1024) void k_final_row(const int* __restrict__ src,
                                                    const float* __restrict__ attn,
                                                    const float* __restrict__ prob,
                                                    const float* __restrict__ Zrow,
                                                    const __bf16* __restrict__ LG,
                                                    float* __restrict__ out) {
    __shared__ int      keys[HT];
    __shared__ float    vals[HT];
    __shared__ unsigned bmap[NBW];
    __shared__ float    red[1024];
    __shared__ int      s_D;
    __shared__ float    s_Zc;

    int r = blockIdx.x;
    int t = r / BB, b = r % BB;
    int tid = threadIdx.x;
    const float* ap = attn + ((size_t)b * TT + t) * SS;

    // ---- build hash (1024 threads) ----
    { int i = tid; keys[i] = -1; vals[i] = 0.f; }   // HT == 1024
    for (int i = tid; i < NBW; i += 1024) bmap[i] = 0u;
    if (tid == 0) s_D = 0;
    __syncthreads();

    if (tid < SS) {
        int idx = src[tid * BB + b];
        float v = ap[tid];
        unsigned h = ((unsigned)idx * 2654435761u) >> 22;
        while (true) {
            int old = atomicCAS(&keys[h], -1, idx);
            if (old == -1 || old == idx) { atomicAdd(&vals[h], v); break; }
            h = (h + 1) & (HT - 1);
        }
    }
    __syncthreads();

    float lsum = 0.f;
    {
        int k = keys[tid];
        bool occ = (k != -1);
        if (occ) {
            lsum = __expf(vals[tid]);
            atomicOr(&bmap[(unsigned)k >> 5], 1u << (k & 31));
        }
        unsigned long long m = __ballot(occ);
        if ((tid & 63) == 0) atomicAdd(&s_D, __popcll(m));
    }
    red[tid] = lsum; __syncthreads();
    for (int st = 512; st > 0; st >>= 1) {
        if (tid < st) red[tid] += red[tid + st];
        __syncthreads();
    }
    if (tid == 0) s_Zc = (float)(VV - s_D) + red[0];
    __syncthreads();

    // ---- stream the row ----
    float p = prob[r];
    float pinvZ = p / Zrow[r];
    float qinvZc = (1.f - p) / s_Zc;

    const __bf16* lrow = LG + (size_t)r * VP;
    float* orow = out + (size_t)r * VV;

    for (int v0 = tid * 8; v0 < VP; v0 += 8192) {
        bf16x8 l8 = *(const bf16x8*)&lrow[v0];
#pragma unroll
        for (int e = 0; e < 8; e++) {
            int v = v0 + e;
            if (v < VV) {
                float l = (float)l8[e];
                float c = 1.f;
                if ((bmap[v >> 5] >> (v & 31)) & 1u) {
                    unsigned h = ((unsigned)v * 2654435761u) >> 22;
                    while (true) {
                        int k = keys[h];
                        if (k == v) { c = __expf(vals[h]); break; }
                        if (k == -1) break;
                        h = (h + 1) & (HT - 1);
                    }
                }
                orow[v] = __logf(pinvZ * __expf(l) + qinvZc * c);
            }
        }
    }
}

// ---------------------------------------------------------------------------
// K4b: fallback — finalize fp32 logits in-place in d_out (R3-validated path).
// ---------------------------------------------------------------------------
#define CHUNKS 6283
__global__ __launch_bounds__(256) void k_final_s(const int* __restrict__ src,
                                                 const float* __restrict__ attn,
                                                 const float* __restrict__ prob,
                                                 const float* __restrict__ Zrow,
                                                 float* __restrict__ out) {
    __shared__ int      keys[HT];
    __shared__ float    vals[HT];
    __shared__ unsigned bmap[NBW];
    __shared__ float    red[256];
    __shared__ int      s_D;
    __shared__ float    s_Zc;

    int r = blockIdx.y;
    int t = r / BB, b = r % BB;
    int tid = threadIdx.x;
    const float* ap = attn + ((size_t)b * TT + t) * SS;
    build_hash(src, ap, b, tid, keys, vals, bmap, red, &s_D, &s_Zc);

    float p = prob[r];
    float pinvZ = p / Zrow[r];
    float qinvZc = (1.f - p) / s_Zc;

    int c0 = blockIdx.x * CHUNKS;
    int c1 = c0 + CHUNKS; if (c1 > VV) c1 = VV;
    float* rowp = out + (size_t)r * VV;

    for (int v = c0 + tid; v < c1; v += 256) {
        float l = rowp[v];
        float c = 1.f;
        if ((bmap[v >> 5] >> (v & 31)) & 1u) {
            unsigned h = ((unsigned)v * 2654435761u) >> 22;
            while (true) {
                int k = keys[h];
                if (k == v) { c = __expf(vals[h]); break; }
                if (k == -1) break;
                h = (h + 1) & (HT - 1);
            }
        }
        rowp[v] = __logf(pinvZ * __expf(l) + qinvZc * c);
    }
}

// ---------------------------------------------------------------------------
extern "C" void kernel_launch(void* const* d_in, const int* in_sizes, int n_in,
                              void* d_out, int out_size, void* d_ws, size_t ws_size,
                              hipStream_t stream) {
    const int*   src_full      = (const int*)d_in[0];   // [S,B]
    const float* decode_output = (const float*)d_in[1]; // [T,B,H]
    const float* decode_attn   = (const float*)d_in[2]; // [B,T,S]
    const float* memory        = (const float*)d_in[3]; // [S,B,H]
    const float* W_gen         = (const float*)d_in[4]; // [H,V]
    const float* b_gen         = (const float*)d_in[5]; // [V]
    const float* W_prob        = (const float*)d_in[6]; // [H]
    const float* b_prob        = (const float*)d_in[7]; // [1]
    float* out = (float*)d_out;                         // [T,B,V]

    float* ws   = (float*)d_ws;
    float* mw   = ws;                        // 4096 floats
    float* prob = ws + 4096;                 // 512
    float* Z    = ws + 4608;                 // 512
    __bf16* Ab  = (__bf16*)(ws + 5120);      // 512*512 bf16 (512 KB = 131072 float slots)
    __bf16* Wt  = (__bf16*)(ws + 5120 + 131072);   // VP*HH bf16 (51.5 MB)
    __bf16* LG  = Wt + (size_t)VP * HH;            // MM*VP bf16 (51.5 MB)

    size_t base_b = (size_t)(5120 + 131072) * sizeof(float);
    size_t wt_b   = (size_t)VP * HH * 2;
    size_t lg_b   = (size_t)MM * VP * 2;
    bool full = ws_size >= base_b + wt_b + lg_b;

    k_castA<<<MM * HH / (256 * 4), 256, 0, stream>>>(decode_output, Ab);
    k_mw<<<SS * BB, 64, 0, stream>>>(memory, W_prob, mw);
    k_prob<<<TT * BB, 64, 0, stream>>>(decode_attn, mw, b_prob, prob);
    hipMemsetAsync(Z, 0, MM * sizeof(float), stream);

    dim3 tgrid(VP / 64, HH / 64);            // (786, 8)
    k_castWT<<<tgrid, 256, 0, stream>>>(W_gen, Wt);

    dim3 ggrid(MM / 128, VP / 128);          // (4, 393)
    if (full) {
        k_gemm3<true><<<ggrid, 512, 0, stream>>>(Ab, Wt, b_gen, nullptr, LG, Z);
        k_final_row<<<MM, 1024, 0, stream>>>(src_full, decode_attn, prob, Z, LG, out);
    } else {
        k_gemm3<false><<<ggrid, 512, 0, stream>>>(Ab, Wt, b_gen, out, nullptr, Z);
        dim3 fgrid((VV + CHUNKS - 1) / CHUNKS, MM);  // (8, 512)
        k_final_s<<<fgrid, 256, 0, stream>>>(src_full, decode_attn, prob, Z, out);
    }
}

// Round 2
// 355.315 us; speedup vs baseline: 1.0704x; 1.0268x over previous
//
#include <hip/hip_runtime.h>
#include <hip/hip_bf16.h>
#include <math.h>

#define VV 50257   // vocab
#define VP 50304   // vocab padded to multiple of 128 (and 16)
#define HH 512     // d_model
#define SS 512     // source length
#define BB 8       // batch
#define TT 64      // decode steps
#define MM (TT*BB) // 512 GEMM rows

typedef __bf16 bf16x2 __attribute__((ext_vector_type(2)));
typedef __bf16 bf16x4 __attribute__((ext_vector_type(4)));
typedef __bf16 bf16x8 __attribute__((ext_vector_type(8)));
typedef float  f32x4  __attribute__((ext_vector_type(4)));

// fp32 -> bf16 RNE
__device__ __forceinline__ __bf16 f2b(float f) {
    unsigned u = __builtin_bit_cast(unsigned, f);
    unsigned r = (u + 0x7fffu + ((u >> 16) & 1u)) >> 16;
    unsigned short s = (unsigned short)r;
    return __builtin_bit_cast(__bf16, s);
}

// async global->LDS, 16B per lane; lds base must be wave-uniform
__device__ __forceinline__ void gl2lds16(const void* g, void* l) {
    __builtin_amdgcn_global_load_lds(
        (const __attribute__((address_space(1))) unsigned*)g,
        (__attribute__((address_space(3))) unsigned*)l, 16, 0, 0);
}

#define WAITV(n) asm volatile("s_waitcnt vmcnt(" #n ")" ::: "memory")

// ---------------------------------------------------------------------------
// L1 fused: blocks [0,256): cast decode_output fp32 -> bf16
//           blocks [256,1280): mw[s,b] = dot(memory[s,b,:], W_prob), 4 rows/blk
// ---------------------------------------------------------------------------
__global__ __launch_bounds__(256) void k_pre(const float* __restrict__ A,
                                             __bf16* __restrict__ Ab,
                                             const float* __restrict__ mem,
                                             const float* __restrict__ Wp,
                                             float* __restrict__ mw) {
    int tid = threadIdx.x;
    if (blockIdx.x < 256) {
        int i = (blockIdx.x * 256 + tid) * 4;
        float4 v = *(const float4*)&A[i];
        bf16x4 o = {f2b(v.x), f2b(v.y), f2b(v.z), f2b(v.w)};
        *(bf16x4*)&Ab[i] = o;
    } else {
        int bx = blockIdx.x - 256;
        int row = bx * 4 + (tid >> 6);        // 0..4095
        int lane = tid & 63;
        const float* mp = mem + (size_t)row * HH;
        float acc = 0.f;
#pragma unroll
        for (int i = 0; i < HH / 64; i++)
            acc += mp[lane + 64 * i] * Wp[lane + 64 * i];
#pragma unroll
        for (int off = 32; off > 0; off >>= 1) acc += __shfl_down(acc, off);
        if (lane == 0) mw[row] = acc;
    }
}

// ---------------------------------------------------------------------------
// L2 fused: blocks [0,512): prob[r]=sigmoid(sum_s attn*mw + b), also Z[r]=0
//           blocks [512,6800): W fp32 [HH][VV] -> Wt bf16 [VP][HH] transpose
// ---------------------------------------------------------------------------
__global__ __launch_bounds__(256) void k_mid(const float* __restrict__ attn,
                                             const float* __restrict__ mw,
                                             const float* __restrict__ bp,
                                             float* __restrict__ prob,
                                             float* __restrict__ Z,
                                             const float* __restrict__ W,
                                             __bf16* __restrict__ Wt) {
    __shared__ float tile[64][65];
    int tid = threadIdx.x;
    if (blockIdx.x < 512) {
        int r = blockIdx.x;
        int t = r / BB, b = r % BB;
        const float* ap = attn + ((size_t)b * TT + t) * SS;
        float acc = ap[tid] * mw[tid * BB + b] +
                    ap[tid + 256] * mw[(tid + 256) * BB + b];
        float* red = &tile[0][0];
        red[tid] = acc; __syncthreads();
        for (int st = 128; st > 0; st >>= 1) {
            if (tid < st) red[tid] += red[tid + st];
            __syncthreads();
        }
        if (tid == 0) {
            prob[r] = 1.f / (1.f + expf(-(red[0] + bp[0])));
            Z[r] = 0.f;
        }
    } else {
        int bx = blockIdx.x - 512;
        int n0 = (bx % (VP / 64)) * 64;
        int k0 = (bx / (VP / 64)) * 64;
#pragma unroll
        for (int i = 0; i < 16; i++) {
            int idx = tid + i * 256;
            int kk = idx >> 6, nn = idx & 63;
            int n = n0 + nn;
            tile[kk][nn] = (n < VV) ? W[(size_t)(k0 + kk) * VV + n] : 0.f;
        }
        __syncthreads();
#pragma unroll
        for (int i = 0; i < 8; i++) {
            int idx = tid + i * 256;
            int nn = idx >> 5, kp = idx & 31;
            bf16x2 o = {f2b(tile[2 * kp][nn]), f2b(tile[2 * kp + 1][nn])};
            *(bf16x2*)&Wt[(size_t)(n0 + nn) * HH + k0 + 2 * kp] = o;
        }
    }
}

// ---------------------------------------------------------------------------
// K3: MFMA GEMM 128x128 tile. NEW SCHEDULE: BK=32, 16 k-iters, 4 LDS buffers,
// 3-tile-deep prefetch with raw s_barrier + COUNTED vmcnt (never 0 in the
// main loop; T4 pattern). Per iter per wave: 2 global_load_lds (1 A seg +
// 1 B seg), 6 ds_read_b128, 8 MFMA. Buffer (it+3)&3 written at iter it was
// last read at iter it-1, whose ds_reads are provably drained before any
// wave passes barrier(it) (lgkmcnt waits precede the MFMAs that precede the
// barrier). k-accumulation order identical to BK=64x2h version.
// ---------------------------------------------------------------------------
template<bool BF16OUT>
__global__ __launch_bounds__(512, 4) void k_gemm4(const __bf16* __restrict__ Ab,
                                                  const __bf16* __restrict__ Wt,
                                                  const float* __restrict__ bias,
                                                  float* __restrict__ Cf,
                                                  __bf16* __restrict__ Cb,
                                                  float* __restrict__ Zrow) {
    __shared__ __bf16 As[4][4096];   // 4 bufs x 8KB (8 segs x 16 rows x 32k)
    __shared__ __bf16 Bs[4][4096];
    __shared__ float zred[128];

    const int tid  = threadIdx.x;
    const int lane = tid & 63;
    const int wave = tid >> 6;          // 0..7
    const int l15  = lane & 15;
    const int quad = lane >> 4;
    const int wr = (wave >> 2) * 64;    // 0 or 64
    const int wc = (wave & 3) * 32;     // 0,32,64,96

    // bijective XCD swizzle over the 1572-block grid (q=196, r=4)
    int L = blockIdx.x + gridDim.x * blockIdx.y;
    int xcd = L & 7, i8 = L >> 3;
    int nid = (xcd < 4 ? xcd * 197 : 4 * 197 + (xcd - 4) * 196) + i8;
    const int row0 = (nid & 3) * 128;
    const int col0 = (nid >> 2) * 128;

    // wave w stages seg w: global (row=seg*16+l15, k=quad*8..+8) ->
    // LDS seg*1024B + 16B*lane (fragment order).
    const size_t offA = (size_t)(row0 + wave * 16 + l15) * HH + quad * 8;
    const size_t offB = (size_t)(col0 + wave * 16 + l15) * HH + quad * 8;

#define STAGE(buf, k0)                                   \
    do {                                                 \
        gl2lds16(Ab + offA + (k0), &As[buf][wave * 512]); \
        gl2lds16(Wt + offB + (k0), &Bs[buf][wave * 512]); \
    } while (0)

    f32x4 acc[4][2] = {};

    STAGE(0, 0);
    STAGE(1, 32);
    STAGE(2, 64);
#pragma unroll
    for (int it = 0; it < 16; ++it) {
        if (it <= 13)      WAITV(4);   // tiles it+1, it+2 stay in flight
        else if (it == 14) WAITV(2);
        else               WAITV(0);
        __builtin_amdgcn_s_barrier();
        if (it < 13) STAGE((it + 3) & 3, (it + 3) * 32);
        const __bf16* Al = &As[it & 3][0];
        const __bf16* Bl = &Bs[it & 3][0];
        bf16x8 af[4], bfv[2];
#pragma unroll
        for (int mt = 0; mt < 4; mt++)
            af[mt] = *(const bf16x8*)&Al[((wr >> 4) + mt) * 512 + lane * 8];
#pragma unroll
        for (int nt = 0; nt < 2; nt++)
            bfv[nt] = *(const bf16x8*)&Bl[((wc >> 4) + nt) * 512 + lane * 8];
#pragma unroll
        for (int mt = 0; mt < 4; mt++)
#pragma unroll
            for (int nt = 0; nt < 2; nt++)
                acc[mt][nt] = __builtin_amdgcn_mfma_f32_16x16x32_bf16(
                    af[mt], bfv[nt], acc[mt][nt], 0, 0, 0);
    }
#undef STAGE

    __syncthreads();
    if (tid < 128) zred[tid] = 0.f;
    __syncthreads();

#pragma unroll
    for (int mt = 0; mt < 4; mt++) {
        float esum[4] = {0.f, 0.f, 0.f, 0.f};
#pragma unroll
        for (int nt = 0; nt < 2; nt++) {
            int c = col0 + wc + nt * 16 + l15;
            if (c < VV) {
                float bv = bias[c];
#pragma unroll
                for (int i = 0; i < 4; i++) {
                    int r = row0 + wr + mt * 16 + quad * 4 + i;
                    float l = acc[mt][nt][i] + bv;
                    if (BF16OUT) Cb[(size_t)r * VP + c] = f2b(l);
                    else         Cf[(size_t)r * VV + c] = l;
                    esum[i] += __expf(l);
                }
            }
        }
#pragma unroll
        for (int i = 0; i < 4; i++) {
            float e = esum[i];
            e += __shfl_xor(e, 1);
            e += __shfl_xor(e, 2);
            e += __shfl_xor(e, 4);
            e += __shfl_xor(e, 8);
            if (l15 == 0)
                atomicAdd(&zred[wr + mt * 16 + quad * 4 + i], e);
        }
    }
    __syncthreads();
    if (tid < 128) atomicAdd(&Zrow[row0 + tid], zred[tid]);
}

// ---------------------------------------------------------------------------
// K4 shared preamble (256-thread version, used by fallback k_final_s)
// ---------------------------------------------------------------------------
#define HT 1024
#define NBW 1572   // ceil(VV/32)

__device__ __forceinline__ void build_hash(const int* __restrict__ src,
                                           const float* __restrict__ ap,
                                           int b, int tid,
                                           int* keys, float* vals, unsigned* bmap,
                                           float* red, int* s_D, float* s_Zc) {
    for (int i = tid; i < HT; i += 256) { keys[i] = -1; vals[i] = 0.f; }
    for (int i = tid; i < NBW; i += 256) bmap[i] = 0u;
    if (tid == 0) *s_D = 0;
    __syncthreads();

    for (int s = tid; s < SS; s += 256) {
        int idx = src[s * BB + b];
        float v = ap[s];
        unsigned h = ((unsigned)idx * 2654435761u) >> 22;
        while (true) {
            int old = atomicCAS(&keys[h], -1, idx);
            if (old == -1 || old == idx) { atomicAdd(&vals[h], v); break; }
            h = (h + 1) & (HT - 1);
        }
    }
    __syncthreads();

    float lsum = 0.f; int dloc = 0;
    for (int i = tid; i < HT; i += 256) {
        int k = keys[i];
        if (k != -1) {
            lsum += __expf(vals[i]); dloc++;
            atomicOr(&bmap[(unsigned)k >> 5], 1u << (k & 31));
        }
    }
    atomicAdd(s_D, dloc);
    red[tid] = lsum; __syncthreads();
    for (int st = 128; st > 0; st >>= 1) {
        if (tid < st) red[tid] += red[tid + st];
        __syncthreads();
    }
    if (tid == 0) *s_Zc = (float)(VV - *s_D) + red[0];
    __syncthreads();
}

// ---------------------------------------------------------------------------
// K4a: finalize from bf16 padded logits — one block per row, 1024 threads.
// ---------------------------------------------------------------------------
__global__ __launch_bounds__(1024) void k_final_row(const int* __restrict__ src,
                                                    const float* __restrict__ attn,
                                                    const float* __restrict__ prob,
                                                    const float* __restrict__ Zrow,
                                                    const __bf16* __restrict__ LG,
                                                    float* __restrict__ out) {
    __shared__ int      keys[HT];
    __shared__ float    vals[HT];
    __shared__ unsigned bmap[NBW];
    __shared__ float    red[1024];
    __shared__ int      s_D;
    __shared__ float    s_Zc;

    int r = blockIdx.x;
    int t = r / BB, b = r % BB;
    int tid = threadIdx.x;
    const float* ap = attn + ((size_t)b * TT + t) * SS;

    { int i = tid; keys[i] = -1; vals[i] = 0.f; }   // HT == 1024
    for (int i = tid; i < NBW; i += 1024) bmap[i] = 0u;
    if (tid == 0) s_D = 0;
    __syncthreads();

    if (tid < SS) {
        int idx = src[tid * BB + b];
        float v = ap[tid];
        unsigned h = ((unsigned)idx * 2654435761u) >> 22;
        while (true) {
            int old = atomicCAS(&keys[h], -1, idx);
            if (old == -1 || old == idx) { atomicAdd(&vals[h], v); break; }
            h = (h + 1) & (HT - 1);
        }
    }
    __syncthreads();

    float lsum = 0.f;
    {
        int k = keys[tid];
        bool occ = (k != -1);
        if (occ) {
            lsum = __expf(vals[tid]);
            atomicOr(&bmap[(unsigned)k >> 5], 1u << (k & 31));
        }
        unsigned long long m = __ballot(occ);
        if ((tid & 63) == 0) atomicAdd(&s_D, __popcll(m));
    }
    red[tid] = lsum; __syncthreads();
    for (int st = 512; st > 0; st >>= 1) {
        if (tid < st) red[tid] += red[tid + st];
        __syncthreads();
    }
    if (tid == 0) s_Zc = (float)(VV - s_D) + red[0];
    __syncthreads();

    float p = prob[r];
    float pinvZ = p / Zrow[r];
    float qinvZc = (1.f - p) / s_Zc;

    const __bf16* lrow = LG + (size_t)r * VP;
    float* orow = out + (size_t)r * VV;

    for (int v0 = tid * 8; v0 < VP; v0 += 8192) {
        bf16x8 l8 = *(const bf16x8*)&lrow[v0];
#pragma unroll
        for (int e = 0; e < 8; e++) {
            int v = v0 + e;
            if (v < VV) {
                float l = (float)l8[e];
                float c = 1.f;
                if ((bmap[v >> 5] >> (v & 31)) & 1u) {
                    unsigned h = ((unsigned)v * 2654435761u) >> 22;
                    while (true) {
                        int k = keys[h];
                        if (k == v) { c = __expf(vals[h]); break; }
                        if (k == -1) break;
                        h = (h + 1) & (HT - 1);
                    }
                }
                orow[v] = __logf(pinvZ * __expf(l) + qinvZc * c);
            }
        }
    }
}

// ---------------------------------------------------------------------------
// K4b: fallback — finalize fp32 logits in-place in d_out
// ---------------------------------------------------------------------------
#define CHUNKS 6283
__global__ __launch_bounds__(256) void k_final_s(const int* __restrict__ src,
                                                 const float* __restrict__ attn,
                                                 const float* __restrict__ prob,
                                                 const float* __restrict__ Zrow,
                                                 float* __restrict__ out) {
    __shared__ int      keys[HT];
    __shared__ float    vals[HT];
    __shared__ unsigned bmap[NBW];
    __shared__ float    red[256];
    __shared__ int      s_D;
    __shared__ float    s_Zc;

    int r = blockIdx.y;
    int t = r / BB, b = r % BB;
    int tid = threadIdx.x;
    const float* ap = attn + ((size_t)b * TT + t) * SS;
    build_hash(src, ap, b, tid, keys, vals, bmap, red, &s_D, &s_Zc);

    float p = prob[r];
    float pinvZ = p / Zrow[r];
    float qinvZc = (1.f - p) / s_Zc;

    int c0 = blockIdx.x * CHUNKS;
    int c1 = c0 + CHUNKS; if (c1 > VV) c1 = VV;
    float* rowp = out + (size_t)r * VV;

    for (int v = c0 + tid; v < c1; v += 256) {
        float l = rowp[v];
        float c = 1.f;
        if ((bmap[v >> 5] >> (v & 31)) & 1u) {
            unsigned h = ((unsigned)v * 2654435761u) >> 22;
            while (true) {
                int k = keys[h];
                if (k == v) { c = __expf(vals[h]); break; }
                if (k == -1) break;
                h = (h + 1) & (HT - 1);
            }
        }
        rowp[v] = __logf(pinvZ * __expf(l) + qinvZc * c);
    }
}

// ---------------------------------------------------------------------------
extern "C" void kernel_launch(void* const* d_in, const int* in_sizes, int n_in,
                              void* d_out, int out_size, void* d_ws, size_t ws_size,
                              hipStream_t stream) {
    const int*   src_full      = (const int*)d_in[0];   // [S,B]
    const float* decode_output = (const float*)d_in[1]; // [T,B,H]
    const float* decode_attn   = (const float*)d_in[2]; // [B,T,S]
    const float* memory        = (const float*)d_in[3]; // [S,B,H]
    const float* W_gen         = (const float*)d_in[4]; // [H,V]
    const float* b_gen         = (const float*)d_in[5]; // [V]
    const float* W_prob        = (const float*)d_in[6]; // [H]
    const float* b_prob        = (const float*)d_in[7]; // [1]
    float* out = (float*)d_out;                         // [T,B,V]

    float* ws   = (float*)d_ws;
    float* mw   = ws;                        // 4096 floats
    float* prob = ws + 4096;                 // 512
    float* Z    = ws + 4608;                 // 512
    __bf16* Ab  = (__bf16*)(ws + 5120);      // 512*512 bf16
    __bf16* Wt  = (__bf16*)(ws + 5120 + 131072);   // VP*HH bf16 (51.5 MB)
    __bf16* LG  = Wt + (size_t)VP * HH;            // MM*VP bf16 (51.5 MB)

    size_t base_b = (size_t)(5120 + 131072) * sizeof(float);
    size_t wt_b   = (size_t)VP * HH * 2;
    size_t lg_b   = (size_t)MM * VP * 2;
    bool full = ws_size >= base_b + wt_b + lg_b;

    // L1: castA + mw   (1280 blocks)
    k_pre<<<1280, 256, 0, stream>>>(decode_output, Ab, memory, W_prob, mw);
    // L2: prob (+Z zero) + castWT   (512 + 6288 blocks)
    k_mid<<<512 + (VP / 64) * (HH / 64), 256, 0, stream>>>(
        decode_attn, mw, b_prob, prob, Z, W_gen, Wt);

    dim3 ggrid(MM / 128, VP / 128);          // (4, 393)
    if (full) {
        k_gemm4<true><<<ggrid, 512, 0, stream>>>(Ab, Wt, b_gen, nullptr, LG, Z);
        k_final_row<<<MM, 1024, 0, stream>>>(src_full, decode_attn, prob, Z, LG, out);
    } else {
        k_gemm4<false><<<ggrid, 512, 0, stream>>>(Ab, Wt, b_gen, out, nullptr, Z);
        dim3 fgrid((VV + CHUNKS - 1) / CHUNKS, MM);  // (8, 512)
        k_final_s<<<fgrid, 256, 0, stream>>>(src_full, decode_attn, prob, Z, out);
    }
}

// Round 3
// 328.873 us; speedup vs baseline: 1.1564x; 1.0804x over previous
//
#include <hip/hip_runtime.h>
#include <hip/hip_bf16.h>
#include <math.h>

#define VV 50257   // vocab
#define VP 50304   // vocab padded to multiple of 128 (and 16)
#define HH 512     // d_model
#define SS 512     // source length
#define BB 8       // batch
#define TT 64      // decode steps
#define MM (TT*BB) // 512 GEMM rows

typedef __bf16 bf16x2 __attribute__((ext_vector_type(2)));
typedef __bf16 bf16x4 __attribute__((ext_vector_type(4)));
typedef __bf16 bf16x8 __attribute__((ext_vector_type(8)));
typedef float  f32x4  __attribute__((ext_vector_type(4)));

// fp32 -> bf16 RNE
__device__ __forceinline__ __bf16 f2b(float f) {
    unsigned u = __builtin_bit_cast(unsigned, f);
    unsigned r = (u + 0x7fffu + ((u >> 16) & 1u)) >> 16;
    unsigned short s = (unsigned short)r;
    return __builtin_bit_cast(__bf16, s);
}

// async global->LDS, 16B per lane; lds base must be wave-uniform
__device__ __forceinline__ void gl2lds16(const void* g, void* l) {
    __builtin_amdgcn_global_load_lds(
        (const __attribute__((address_space(1))) unsigned*)g,
        (__attribute__((address_space(3))) unsigned*)l, 16, 0, 0);
}

#define WAITV(n) asm volatile("s_waitcnt vmcnt(" #n ")" ::: "memory")

// ---------------------------------------------------------------------------
// L1 fused: blocks [0,256): cast decode_output fp32 -> bf16
//           blocks [256,1280): mw[s,b] = dot(memory[s,b,:], W_prob), 4 rows/blk
// ---------------------------------------------------------------------------
__global__ __launch_bounds__(256) void k_pre(const float* __restrict__ A,
                                             __bf16* __restrict__ Ab,
                                             const float* __restrict__ mem,
                                             const float* __restrict__ Wp,
                                             float* __restrict__ mw) {
    int tid = threadIdx.x;
    if (blockIdx.x < 256) {
        int i = (blockIdx.x * 256 + tid) * 4;
        float4 v = *(const float4*)&A[i];
        bf16x4 o = {f2b(v.x), f2b(v.y), f2b(v.z), f2b(v.w)};
        *(bf16x4*)&Ab[i] = o;
    } else {
        int bx = blockIdx.x - 256;
        int row = bx * 4 + (tid >> 6);        // 0..4095
        int lane = tid & 63;
        const float* mp = mem + (size_t)row * HH;
        float acc = 0.f;
#pragma unroll
        for (int i = 0; i < HH / 64; i++)
            acc += mp[lane + 64 * i] * Wp[lane + 64 * i];
#pragma unroll
        for (int off = 32; off > 0; off >>= 1) acc += __shfl_down(acc, off);
        if (lane == 0) mw[row] = acc;
    }
}

// ---------------------------------------------------------------------------
// L2 fused: blocks [0,1572): W fp32 [HH][VV] -> Wt bf16 [VP][HH].
//   Each block owns a 32-vocab strip over FULL K=512: output rows are
//   written as contiguous 1KB bursts (perfect coalescing), vs the old
//   64x64-tile version's 128B segments. Two-step via LDS:
//   fp32 tile[32k][32n] -> transpose+cvt -> Wo[32n][512k] bf16 -> burst out.
//   Global reads stay scalar: W rows are only 4B-aligned (VV odd).
// blocks [1572,2084): prob[r]=sigmoid(sum_s attn*mw + b); also Z[r]=0.
// ---------------------------------------------------------------------------
__global__ __launch_bounds__(256) void k_wt(const float* __restrict__ W,
                                            __bf16* __restrict__ Wt,
                                            const float* __restrict__ attn,
                                            const float* __restrict__ mw,
                                            const float* __restrict__ bp,
                                            float* __restrict__ prob,
                                            float* __restrict__ Z) {
    __shared__ float tile[32][33];       // 4.2 KB (prob path aliases as red[])
    __shared__ __bf16 Wo[32][520];       // 33.3 KB, +8 bf16 row pad (bank spread)
    int tid = threadIdx.x;

    if (blockIdx.x < VP / 32) {
        int n0 = blockIdx.x * 32;
        int nn = tid >> 3, ks = (tid & 7) * 4;     // transpose-phase mapping
        for (int kc = 0; kc < 16; kc++) {
            int k0 = kc * 32;
            // load 32k x 32n fp32, coalesced 128B per k-row
#pragma unroll
            for (int rd = 0; rd < 4; rd++) {
                int idx = rd * 256 + tid;
                int kk = idx >> 5, nc = idx & 31;
                int n = n0 + nc;
                tile[kk][nc] = (n < VV) ? W[(size_t)(k0 + kk) * VV + n] : 0.f;
            }
            __syncthreads();
            // transpose + convert: thread -> (n=nn, k=k0+ks..+4), 8B LDS write
            bf16x4 o = {f2b(tile[ks][nn]), f2b(tile[ks + 1][nn]),
                        f2b(tile[ks + 2][nn]), f2b(tile[ks + 3][nn])};
            *(bf16x4*)&Wo[nn][k0 + ks] = o;
            __syncthreads();
        }
        // burst out: 32 rows x 1KB fully contiguous
#pragma unroll
        for (int i = 0; i < 8; i++) {
            int r = i * 4 + (tid >> 6);
            int c = (tid & 63) * 8;
            *(bf16x8*)&Wt[(size_t)(n0 + r) * HH + c] = *(const bf16x8*)&Wo[r][c];
        }
    } else {
        int r = blockIdx.x - VP / 32;
        int t = r / BB, b = r % BB;
        const float* ap = attn + ((size_t)b * TT + t) * SS;
        float acc = ap[tid] * mw[tid * BB + b] +
                    ap[tid + 256] * mw[(tid + 256) * BB + b];
        float* red = &tile[0][0];
        red[tid] = acc; __syncthreads();
        for (int st = 128; st > 0; st >>= 1) {
            if (tid < st) red[tid] += red[tid + st];
            __syncthreads();
        }
        if (tid == 0) {
            prob[r] = 1.f / (1.f + expf(-(red[0] + bp[0])));
            Z[r] = 0.f;
        }
    }
}

// ---------------------------------------------------------------------------
// K3: MFMA GEMM 128x128 tile, BK=32, 16 k-iters. 3 LDS buffers (48.5 KB ->
// 3 blocks/CU, 24 waves/CU), prefetch depth 2, raw s_barrier + counted
// vmcnt(2) (never 0 in the main loop). s_setprio(1) around the MFMA cluster.
// k-accumulation order identical to previous rounds (bit-identical numerics).
// ---------------------------------------------------------------------------
template<bool BF16OUT>
__global__ __launch_bounds__(512, 6) void k_gemm5(const __bf16* __restrict__ Ab,
                                                  const __bf16* __restrict__ Wt,
                                                  const float* __restrict__ bias,
                                                  float* __restrict__ Cf,
                                                  __bf16* __restrict__ Cb,
                                                  float* __restrict__ Zrow) {
    __shared__ __bf16 As[3][4096];   // 3 bufs x 8KB
    __shared__ __bf16 Bs[3][4096];
    __shared__ float zred[128];

    const int tid  = threadIdx.x;
    const int lane = tid & 63;
    const int wave = tid >> 6;          // 0..7
    const int l15  = lane & 15;
    const int quad = lane >> 4;
    const int wr = (wave >> 2) * 64;    // 0 or 64
    const int wc = (wave & 3) * 32;     // 0,32,64,96

    // bijective XCD swizzle over the 1572-block grid (q=196, r=4)
    int L = blockIdx.x + gridDim.x * blockIdx.y;
    int xcd = L & 7, i8 = L >> 3;
    int nid = (xcd < 4 ? xcd * 197 : 4 * 197 + (xcd - 4) * 196) + i8;
    const int row0 = (nid & 3) * 128;
    const int col0 = (nid >> 2) * 128;

    // wave w stages seg w: global (row=seg*16+l15, k=quad*8..+8) ->
    // LDS seg*1024B + 16B*lane (fragment order).
    const size_t offA = (size_t)(row0 + wave * 16 + l15) * HH + quad * 8;
    const size_t offB = (size_t)(col0 + wave * 16 + l15) * HH + quad * 8;

#define STAGE(buf, k0)                                    \
    do {                                                  \
        gl2lds16(Ab + offA + (k0), &As[buf][wave * 512]); \
        gl2lds16(Wt + offB + (k0), &Bs[buf][wave * 512]); \
    } while (0)

    f32x4 acc[4][2] = {};

    STAGE(0, 0);
    STAGE(1, 32);
#pragma unroll
    for (int it = 0; it < 16; ++it) {
        if (it < 15) WAITV(2);   // wait tile it; keep tile it+1 in flight
        else         WAITV(0);
        __builtin_amdgcn_s_barrier();
        if (it < 14) STAGE((it + 2) % 3, (it + 2) * 32);
        const __bf16* Al = &As[it % 3][0];
        const __bf16* Bl = &Bs[it % 3][0];
        bf16x8 af[4], bfv[2];
#pragma unroll
        for (int mt = 0; mt < 4; mt++)
            af[mt] = *(const bf16x8*)&Al[((wr >> 4) + mt) * 512 + lane * 8];
#pragma unroll
        for (int nt = 0; nt < 2; nt++)
            bfv[nt] = *(const bf16x8*)&Bl[((wc >> 4) + nt) * 512 + lane * 8];
        __builtin_amdgcn_s_setprio(1);
#pragma unroll
        for (int mt = 0; mt < 4; mt++)
#pragma unroll
            for (int nt = 0; nt < 2; nt++)
                acc[mt][nt] = __builtin_amdgcn_mfma_f32_16x16x32_bf16(
                    af[mt], bfv[nt], acc[mt][nt], 0, 0, 0);
        __builtin_amdgcn_s_setprio(0);
    }
#undef STAGE

    __syncthreads();
    if (tid < 128) zred[tid] = 0.f;
    __syncthreads();

#pragma unroll
    for (int mt = 0; mt < 4; mt++) {
        float esum[4] = {0.f, 0.f, 0.f, 0.f};
#pragma unroll
        for (int nt = 0; nt < 2; nt++) {
            int c = col0 + wc + nt * 16 + l15;
            if (c < VV) {
                float bv = bias[c];
#pragma unroll
                for (int i = 0; i < 4; i++) {
                    int r = row0 + wr + mt * 16 + quad * 4 + i;
                    float l = acc[mt][nt][i] + bv;
                    if (BF16OUT) Cb[(size_t)r * VP + c] = f2b(l);
                    else         Cf[(size_t)r * VV + c] = l;
                    esum[i] += __expf(l);
                }
            }
        }
#pragma unroll
        for (int i = 0; i < 4; i++) {
            float e = esum[i];
            e += __shfl_xor(e, 1);
            e += __shfl_xor(e, 2);
            e += __shfl_xor(e, 4);
            e += __shfl_xor(e, 8);
            if (l15 == 0)
                atomicAdd(&zred[wr + mt * 16 + quad * 4 + i], e);
        }
    }
    __syncthreads();
    if (tid < 128) atomicAdd(&Zrow[row0 + tid], zred[tid]);
}

// ---------------------------------------------------------------------------
// K4 shared preamble (256-thread version, used by fallback k_final_s)
// ---------------------------------------------------------------------------
#define HT 1024
#define NBW 1572   // ceil(VV/32)

__device__ __forceinline__ void build_hash(const int* __restrict__ src,
                                           const float* __restrict__ ap,
                                           int b, int tid,
                                           int* keys, float* vals, unsigned* bmap,
                                           float* red, int* s_D, float* s_Zc) {
    for (int i = tid; i < HT; i += 256) { keys[i] = -1; vals[i] = 0.f; }
    for (int i = tid; i < NBW; i += 256) bmap[i] = 0u;
    if (tid == 0) *s_D = 0;
    __syncthreads();

    for (int s = tid; s < SS; s += 256) {
        int idx = src[s * BB + b];
        float v = ap[s];
        unsigned h = ((unsigned)idx * 2654435761u) >> 22;
        while (true) {
            int old = atomicCAS(&keys[h], -1, idx);
            if (old == -1 || old == idx) { atomicAdd(&vals[h], v); break; }
            h = (h + 1) & (HT - 1);
        }
    }
    __syncthreads();

    float lsum = 0.f; int dloc = 0;
    for (int i = tid; i < HT; i += 256) {
        int k = keys[i];
        if (k != -1) {
            lsum += __expf(vals[i]); dloc++;
            atomicOr(&bmap[(unsigned)k >> 5], 1u << (k & 31));
        }
    }
    atomicAdd(s_D, dloc);
    red[tid] = lsum; __syncthreads();
    for (int st = 128; st > 0; st >>= 1) {
        if (tid < st) red[tid] += red[tid + st];
        __syncthreads();
    }
    if (tid == 0) *s_Zc = (float)(VV - *s_D) + red[0];
    __syncthreads();
}

// ---------------------------------------------------------------------------
// K4a: finalize from bf16 padded logits. Grid (2, MM): each block handles
// half the vocab of one row (2x parallelism vs 1 block/row). Clean 8-packs
// (bitmap byte == 0, ~92%) take a guard-free path: no hash probe, no bounds
// check, straight exp/log + unconditional coalesced stores.
// ---------------------------------------------------------------------------
#define HV (VP / 2)   // 25152, multiple of 8
__global__ __launch_bounds__(1024) void k_final2(const int* __restrict__ src,
                                                 const float* __restrict__ attn,
                                                 const float* __restrict__ prob,
                                                 const float* __restrict__ Zrow,
                                                 const __bf16* __restrict__ LG,
                                                 float* __restrict__ out) {
    __shared__ int      keys[HT];
    __shared__ float    vals[HT];
    __shared__ unsigned bmap[NBW];
    __shared__ float    red[1024];
    __shared__ int      s_D;
    __shared__ float    s_Zc;

    int r = blockIdx.y;
    int half = blockIdx.x;
    int t = r / BB, b = r % BB;
    int tid = threadIdx.x;
    const float* ap = attn + ((size_t)b * TT + t) * SS;

    // ---- build hash (1024 threads; HT == 1024) ----
    { keys[tid] = -1; vals[tid] = 0.f; }
    for (int i = tid; i < NBW; i += 1024) bmap[i] = 0u;
    if (tid == 0) s_D = 0;
    __syncthreads();

    if (tid < SS) {
        int idx = src[tid * BB + b];
        float v = ap[tid];
        unsigned h = ((unsigned)idx * 2654435761u) >> 22;
        while (true) {
            int old = atomicCAS(&keys[h], -1, idx);
            if (old == -1 || old == idx) { atomicAdd(&vals[h], v); break; }
            h = (h + 1) & (HT - 1);
        }
    }
    __syncthreads();

    float lsum = 0.f;
    {
        int k = keys[tid];
        bool occ = (k != -1);
        if (occ) {
            lsum = __expf(vals[tid]);
            atomicOr(&bmap[(unsigned)k >> 5], 1u << (k & 31));
        }
        unsigned long long m = __ballot(occ);
        if ((tid & 63) == 0) atomicAdd(&s_D, __popcll(m));
    }
    red[tid] = lsum; __syncthreads();
    for (int st = 512; st > 0; st >>= 1) {
        if (tid < st) red[tid] += red[tid + st];
        __syncthreads();
    }
    if (tid == 0) s_Zc = (float)(VV - s_D) + red[0];
    __syncthreads();

    float p = prob[r];
    float pinvZ = p / Zrow[r];
    float qinvZc = (1.f - p) / s_Zc;

    const __bf16* lrow = LG + (size_t)r * VP;
    float* orow = out + (size_t)r * VV;

    int base = half * HV;
    for (int v0 = base + tid * 8; v0 < base + HV; v0 += 8192) {
        bf16x8 l8 = *(const bf16x8*)&lrow[v0];
        unsigned bits = (bmap[v0 >> 5] >> (v0 & 31)) & 0xFFu;  // v0%8==0
        if (bits == 0u && v0 + 8 <= VV) {
            // clean fast path: no hash, no guards
#pragma unroll
            for (int e = 0; e < 8; e++)
                orow[v0 + e] = __logf(pinvZ * __expf((float)l8[e]) + qinvZc);
        } else {
#pragma unroll
            for (int e = 0; e < 8; e++) {
                int v = v0 + e;
                if (v < VV) {
                    float l = (float)l8[e];
                    float c = 1.f;
                    if ((bits >> e) & 1u) {
                        unsigned h = ((unsigned)v * 2654435761u) >> 22;
                        while (true) {
                            int k = keys[h];
                            if (k == v) { c = __expf(vals[h]); break; }
                            if (k == -1) break;
                            h = (h + 1) & (HT - 1);
                        }
                    }
                    orow[v] = __logf(pinvZ * __expf(l) + qinvZc * c);
                }
            }
        }
    }
}

// ---------------------------------------------------------------------------
// K4b: fallback — finalize fp32 logits in-place in d_out
// ---------------------------------------------------------------------------
#define CHUNKS 6283
__global__ __launch_bounds__(256) void k_final_s(const int* __restrict__ src,
                                                 const float* __restrict__ attn,
                                                 const float* __restrict__ prob,
                                                 const float* __restrict__ Zrow,
                                                 float* __restrict__ out) {
    __shared__ int      keys[HT];
    __shared__ float    vals[HT];
    __shared__ unsigned bmap[NBW];
    __shared__ float    red[256];
    __shared__ int      s_D;
    __shared__ float    s_Zc;

    int r = blockIdx.y;
    int t = r / BB, b = r % BB;
    int tid = threadIdx.x;
    const float* ap = attn + ((size_t)b * TT + t) * SS;
    build_hash(src, ap, b, tid, keys, vals, bmap, red, &s_D, &s_Zc);

    float p = prob[r];
    float pinvZ = p / Zrow[r];
    float qinvZc = (1.f - p) / s_Zc;

    int c0 = blockIdx.x * CHUNKS;
    int c1 = c0 + CHUNKS; if (c1 > VV) c1 = VV;
    float* rowp = out + (size_t)r * VV;

    for (int v = c0 + tid; v < c1; v += 256) {
        float l = rowp[v];
        float c = 1.f;
        if ((bmap[v >> 5] >> (v & 31)) & 1u) {
            unsigned h = ((unsigned)v * 2654435761u) >> 22;
            while (true) {
                int k = keys[h];
                if (k == v) { c = __expf(vals[h]); break; }
                if (k == -1) break;
                h = (h + 1) & (HT - 1);
            }
        }
        rowp[v] = __logf(pinvZ * __expf(l) + qinvZc * c);
    }
}

// ---------------------------------------------------------------------------
extern "C" void kernel_launch(void* const* d_in, const int* in_sizes, int n_in,
                              void* d_out, int out_size, void* d_ws, size_t ws_size,
                              hipStream_t stream) {
    const int*   src_full      = (const int*)d_in[0];   // [S,B]
    const float* decode_output = (const float*)d_in[1]; // [T,B,H]
    const float* decode_attn   = (const float*)d_in[2]; // [B,T,S]
    const float* memory        = (const float*)d_in[3]; // [S,B,H]
    const float* W_gen         = (const float*)d_in[4]; // [H,V]
    const float* b_gen         = (const float*)d_in[5]; // [V]
    const float* W_prob        = (const float*)d_in[6]; // [H]
    const float* b_prob        = (const float*)d_in[7]; // [1]
    float* out = (float*)d_out;                         // [T,B,V]

    float* ws   = (float*)d_ws;
    float* mw   = ws;                        // 4096 floats
    float* prob = ws + 4096;                 // 512
    float* Z    = ws + 4608;                 // 512
    __bf16* Ab  = (__bf16*)(ws + 5120);      // 512*512 bf16
    __bf16* Wt  = (__bf16*)(ws + 5120 + 131072);   // VP*HH bf16 (51.5 MB)
    __bf16* LG  = Wt + (size_t)VP * HH;            // MM*VP bf16 (51.5 MB)

    size_t base_b = (size_t)(5120 + 131072) * sizeof(float);
    size_t wt_b   = (size_t)VP * HH * 2;
    size_t lg_b   = (size_t)MM * VP * 2;
    bool full = ws_size >= base_b + wt_b + lg_b;

    // L1: castA + mw   (1280 blocks)
    k_pre<<<1280, 256, 0, stream>>>(decode_output, Ab, memory, W_prob, mw);
    // L2: castWT strips (1572) + prob/Z (512)
    k_wt<<<VP / 32 + 512, 256, 0, stream>>>(W_gen, Wt, decode_attn, mw, b_prob,
                                            prob, Z);

    dim3 ggrid(MM / 128, VP / 128);          // (4, 393)
    if (full) {
        k_gemm5<true><<<ggrid, 512, 0, stream>>>(Ab, Wt, b_gen, nullptr, LG, Z);
        dim3 fgrid(2, MM);                   // (2, 512)
        k_final2<<<fgrid, 1024, 0, stream>>>(src_full, decode_attn, prob, Z, LG, out);
    } else {
        k_gemm5<false><<<ggrid, 512, 0, stream>>>(Ab, Wt, b_gen, out, nullptr, Z);
        dim3 fgrid((VV + CHUNKS - 1) / CHUNKS, MM);  // (8, 512)
        k_final_s<<<fgrid, 256, 0, stream>>>(src_full, decode_attn, prob, Z, out);
    }
}